// Round 3
// baseline (210.850 us; speedup 1.0000x reference)
//
#include <hip/hip_runtime.h>
#include <math.h>

#define L2PI4      7.3515082656373812f   // 4*log(2*pi)
#define HALF_L2PI4 3.6757541328186906f   // 2*log(2*pi)
#define LOG2E      1.4426950408889634f
#define LN2        0.6931471805599453f
#define C_HQ       0.7213475204444817f   // 0.5*log2(e)

__device__ __forceinline__ float frcp(float x) { return __builtin_amdgcn_rcpf(x); }

__device__ __forceinline__ void barrier_wait(int* c, int target) {
    long it = 0;
    while (__hip_atomic_load(c, __ATOMIC_ACQUIRE, __HIP_MEMORY_SCOPE_AGENT) < target) {
        __builtin_amdgcn_s_sleep(8);
        if (++it > 50000000L) break;   // bail-out: wrong answer beats a hang
    }
}

// ---------------------------------------------------------------------------
// kP: zero the per-level barrier counters; precompute exp(2*trans_var_*).
// ---------------------------------------------------------------------------
__global__ __launch_bounds__(256) void kP(
    const float* __restrict__ a, const float* __restrict__ b,
    const float* __restrict__ c,
    float* __restrict__ oa, float* __restrict__ ob, float* __restrict__ oc,
    int* __restrict__ cnt)
{
    int i = blockIdx.x * 256 + threadIdx.x;
    if (i < 2000) {
        oa[i] = __expf(2.0f * a[i]);
        ob[i] = __expf(2.0f * b[i]);
        oc[i] = __expf(2.0f * c[i]);
    }
    if (i < 512) cnt[i] = 0;
}

// ---------------------------------------------------------------------------
// kB phase (shared): combine lr(L)+lr(R)+tw, score vs parent state (gm_full).
// Emits either intermediate (w2 = (w-2log2pi)*log2e, mu, ve=exp(2*var)) or,
// at the final level, (w, mu, var) into d_out layout.
// ---------------------------------------------------------------------------
__device__ __forceinline__ void gm_full_dim(
    float m1, float v1, float v1s, float m2, float v2, float v2s,
    float& scale, float& pmu, float& pvar, float& pve)
{
    float s  = v1s + v2s;
    float rs = frcp(s);
    float ls = __builtin_amdgcn_logf(s) * LN2;   // natural log
    float df = m1 - m2;
    scale += ls + df * df * rs;
    pmu  = fmaf(m1, v2s, m2 * v1s) * rs;
    pvar = v1 + v2 - 0.5f * ls;
    pve  = v1s * v2s * rs;
}

__device__ __forceinline__ void doKB(
    int p, const float* __restrict__ lr, const float* __restrict__ tw,
    const float4* __restrict__ tm4, const float4* __restrict__ tv4,
    const float4* __restrict__ te4,
    const float* s_sw, const float* s_sm, const float* s_sv, const float* s_sve,
    float* __restrict__ w2o, float4* __restrict__ muo4, float4* __restrict__ veo4,
    int finalLvl, float* __restrict__ outw, float4* __restrict__ outmu4,
    float4* __restrict__ outvar4, int tid)
{
    const float* lrL = lr + (size_t)p * 1000;
    const float* lrR = lrL + 500;
    for (int e = tid; e < 2000; e += 256) {
        int c = e & 3, ks = (e >> 2) & 3, r = e >> 4;
        int lrc = r % 5, r2 = r / 5, llc = r2 % 5, lp = r2 / 5;
        int t4 = ((lp * 5 + llc) * 5 + lrc) * 4 + c;
        float csv = __hip_atomic_load(&lrL[t4], __ATOMIC_RELAXED, __HIP_MEMORY_SCOPE_AGENT)
                  + __hip_atomic_load(&lrR[t4], __ATOMIC_RELAXED, __HIP_MEMORY_SCOPE_AGENT)
                  + tw[t4];
        float4 m2 = tm4[t4], v2 = tv4[t4], e2 = te4[t4];
        int sidx = (lp * 4 + ks) * 4;
        float base = csv + s_sw[lp * 4 + ks] - HALF_L2PI4;
        float scale = 0.f;
        float4 pmu, pvar, pve;
        gm_full_dim(s_sm[sidx+0], s_sv[sidx+0], s_sve[sidx+0], m2.x, v2.x, e2.x, scale, pmu.x, pvar.x, pve.x);
        gm_full_dim(s_sm[sidx+1], s_sv[sidx+1], s_sve[sidx+1], m2.y, v2.y, e2.y, scale, pmu.y, pvar.y, pve.y);
        gm_full_dim(s_sm[sidx+2], s_sv[sidx+2], s_sve[sidx+2], m2.z, v2.z, e2.z, scale, pmu.z, pvar.z, pve.z);
        gm_full_dim(s_sm[sidx+3], s_sv[sidx+3], s_sve[sidx+3], m2.w, v2.w, e2.w, scale, pmu.w, pvar.w, pve.w);
        float w = fmaf(-0.5f, scale, base);
        if (finalLvl) {
            outw[e]    = w;
            outmu4[e]  = pmu;
            outvar4[e] = pvar;
        } else {
            size_t ob = (size_t)p * 2000 + e;
            w2o[ob]  = (w - HALF_L2PI4) * LOG2E;
            muo4[ob] = pmu;
            veo4[ob] = pve;
        }
    }
}

// ---------------------------------------------------------------------------
// kL1: level-1 (children = leaves, K=4), fused with kB via per-parent barrier.
// block = child node (bid = 2p+side).
// ---------------------------------------------------------------------------
__global__ __launch_bounds__(256) void kL1(
    const float* __restrict__ sw, const float* __restrict__ smu,
    const float* __restrict__ svar,
    const float4* __restrict__ tmL4, const float4* __restrict__ tvL4,
    const float4* __restrict__ tmR4, const float4* __restrict__ tvR4,
    float* __restrict__ lr, int* __restrict__ cnt,
    const float* __restrict__ tw, const float4* __restrict__ tmp4,
    const float4* __restrict__ tvp4, const float4* __restrict__ tep4,
    int off,
    float* __restrict__ w2o, float4* __restrict__ muo4, float4* __restrict__ veo4)
{
    int bid = blockIdx.x, p = bid >> 1, side = bid & 1, cn = bid;
    int tid = threadIdx.x;
    __shared__ float s_cm[80], s_cve[80], s_cw2[20];
    __shared__ float s_sw[20], s_sm[80], s_sv[80], s_sve[80];
    if (tid < 80) {
        s_cm[tid]  = smu[cn * 80 + tid];
        s_cve[tid] = __expf(2.f * svar[cn * 80 + tid]);
        if (tid < 20) s_cw2[tid] = (sw[cn * 20 + tid] - HALF_L2PI4) * LOG2E;
    }
    if (side == 0 && tid >= 128 && tid < 208) {
        int i = tid - 128, node = off + p;
        s_sm[i] = smu[node * 80 + i];
        float v = svar[node * 80 + i];
        s_sv[i] = v; s_sve[i] = __expf(2.f * v);
        if (i < 20) s_sw[i] = sw[node * 20 + i];
    }
    __syncthreads();
    const float4* tm = side ? tmR4 : tmL4;
    const float4* tv = side ? tvR4 : tvL4;
    for (int e = tid; e < 500; e += 256) {
        int c = e & 3, r = e >> 2;
        int lo = r % 5, r2 = r / 5, lp = r2 % 5, lc2 = r2 / 5;
        int idx = side ? (((lp * 5 + lo) * 5 + lc2) * 4 + c)
                       : (((lp * 5 + lc2) * 5 + lo) * 4 + c);
        float4 tmo = tm[idx], tvo = tv[idx];
        float vals[4];
        #pragma unroll
        for (int k = 0; k < 4; ++k) {
            int ci = (lc2 * 4 + k) * 4;
            float s0 = s_cve[ci+0] + tvo.x, s1 = s_cve[ci+1] + tvo.y;
            float s2 = s_cve[ci+2] + tvo.z, s3 = s_cve[ci+3] + tvo.w;
            float d0 = s_cm[ci+0] - tmo.x, d1 = s_cm[ci+1] - tmo.y;
            float d2 = s_cm[ci+2] - tmo.z, d3 = s_cm[ci+3] - tmo.w;
            float p01 = s0 * s1, p23 = s2 * s3;
            float q01 = fmaf(d0 * d0, s1, d1 * d1 * s0);
            float q23 = fmaf(d2 * d2, s3, d3 * d3 * s2);
            float P = p01 * p23;
            float Q = fmaf(q01, p23, q23 * p01);
            float QP = Q * frcp(P);
            vals[k] = fmaf(-0.5f, __builtin_amdgcn_logf(P),
                           fmaf(-C_HQ, QP, s_cw2[lc2 * 4 + k]));
        }
        float M = fmaxf(fmaxf(vals[0], vals[1]), fmaxf(vals[2], vals[3]));
        float S = __builtin_amdgcn_exp2f(vals[0]-M) + __builtin_amdgcn_exp2f(vals[1]-M)
                + __builtin_amdgcn_exp2f(vals[2]-M) + __builtin_amdgcn_exp2f(vals[3]-M);
        float rr = (M + __builtin_amdgcn_logf(S)) * LN2;
        __hip_atomic_store(&lr[(size_t)cn * 500 + idx], rr,
                           __ATOMIC_RELAXED, __HIP_MEMORY_SCOPE_AGENT);
    }
    __syncthreads();
    if (tid == 0) { __threadfence(); atomicAdd(cnt + p, 1); }
    if (side) return;
    if (tid == 0) barrier_wait(cnt + p, 2);
    __syncthreads();
    doKB(p, lr, tw, tmp4, tvp4, tep4, s_sw, s_sm, s_sv, s_sve,
         w2o, muo4, veo4, 0, nullptr, nullptr, nullptr, tid);
}

// ---------------------------------------------------------------------------
// kLvl: one kernel per K=400 level. block = (p, side, lc): 100 outputs, child
// fragment register-cached once (reused across all 5 lp). sl==0 block runs the
// kB phase after the per-parent barrier (target 10).
// ---------------------------------------------------------------------------
__global__ __launch_bounds__(256) void kLvl(
    const float* __restrict__ cw2, const float4* __restrict__ cmu4,
    const float4* __restrict__ cve4,
    const float* __restrict__ tmL, const float* __restrict__ tvL,
    const float* __restrict__ tmR, const float* __restrict__ tvR,
    float* __restrict__ lr, int* __restrict__ cnt, int log2m,
    const float* __restrict__ tw, const float4* __restrict__ tmp4,
    const float4* __restrict__ tvp4, const float4* __restrict__ tep4,
    const float* __restrict__ sw_all, const float* __restrict__ smu,
    const float* __restrict__ svar, int off,
    float* __restrict__ w2o, float4* __restrict__ muo4, float4* __restrict__ veo4,
    int finalLvl, float* __restrict__ outw, float4* __restrict__ outmu4,
    float4* __restrict__ outvar4)
{
    int bid = blockIdx.x;
    int p = bid & ((1 << log2m) - 1), sl = bid >> log2m;
    int side = sl / 5, lc = sl % 5;
    int tid = threadIdx.x, lane = tid & 63, wave = tid >> 6;

    __shared__ float4 s_tm[100], s_tv[100];
    __shared__ float s_sw[20], s_sm[80], s_sv[80], s_sve[80];

    const float* tmf = side ? tmR : tmL;
    const float* tvf = side ? tvR : tvL;
    for (int i = tid; i < 400; i += 256) {
        int o = i >> 2, d = i & 3;
        int lp = o / 20, t = o % 20;
        int g = side ? (lp * 100 + (t >> 2) * 20 + lc * 4 + (t & 3))
                     : (lp * 100 + lc * 20 + t);
        ((float*)s_tm)[i] = tmf[g * 4 + d];
        ((float*)s_tv)[i] = tvf[g * 4 + d];
    }
    if (sl == 0) {
        int node = off + p;
        for (int i = tid; i < 80; i += 256) {
            s_sm[i] = smu[node * 80 + i];
            float v = svar[node * 80 + i];
            s_sv[i] = v; s_sve[i] = __expf(2.f * v);
        }
        if (tid < 20) s_sw[tid] = sw_all[node * 20 + tid];
    }

    int cn = 2 * p + side;
    const float4* cmb = cmu4 + (size_t)(cn * 5 + lc) * 400;
    const float4* cvb = cve4 + (size_t)(cn * 5 + lc) * 400;
    const float*  cwb = cw2  + (size_t)(cn * 5 + lc) * 400;
    float4 cm[7], cv[7]; float w2r[7];
    #pragma unroll
    for (int i = 0; i < 7; ++i) {
        int k = lane + (i << 6);
        bool ok = (k < 400);
        cm[i]  = ok ? cmb[k] : make_float4(0.f, 0.f, 0.f, 0.f);
        cv[i]  = ok ? cvb[k] : make_float4(1.f, 1.f, 1.f, 1.f);
        w2r[i] = ok ? cwb[k] : -1e30f;
    }
    __syncthreads();

    size_t lrb = (size_t)cn * 500;
    #pragma unroll 2
    for (int j = 0; j < 25; ++j) {
        int o = j * 4 + wave;
        float4 tmo = s_tm[o], tvo = s_tv[o];
        float vals[7];
        #pragma unroll
        for (int i = 0; i < 7; ++i) {
            float s0 = cv[i].x + tvo.x, s1 = cv[i].y + tvo.y;
            float s2 = cv[i].z + tvo.z, s3 = cv[i].w + tvo.w;
            float d0 = cm[i].x - tmo.x, d1 = cm[i].y - tmo.y;
            float d2 = cm[i].z - tmo.z, d3 = cm[i].w - tmo.w;
            float p01 = s0 * s1, p23 = s2 * s3;
            float q01 = fmaf(d0 * d0, s1, d1 * d1 * s0);
            float q23 = fmaf(d2 * d2, s3, d3 * d3 * s2);
            float P = p01 * p23;
            float Q = fmaf(q01, p23, q23 * p01);
            float QP = Q * frcp(P);
            vals[i] = fmaf(-0.5f, __builtin_amdgcn_logf(P),
                           fmaf(-C_HQ, QP, w2r[i]));
        }
        float M = vals[0];
        #pragma unroll
        for (int i = 1; i < 7; ++i) M = fmaxf(M, vals[i]);
        #pragma unroll
        for (int s = 32; s; s >>= 1) M = fmaxf(M, __shfl_xor(M, s));
        float S = 0.f;
        #pragma unroll
        for (int i = 0; i < 7; ++i) S += __builtin_amdgcn_exp2f(vals[i] - M);
        #pragma unroll
        for (int s = 32; s; s >>= 1) S += __shfl_xor(S, s);
        if (lane == 0) {
            int lp = o / 20, t = o % 20;
            int idx = side ? (lp * 100 + (t >> 2) * 20 + lc * 4 + (t & 3))
                           : (lp * 100 + lc * 20 + t);
            float rr = (M + __builtin_amdgcn_logf(S)) * LN2;
            __hip_atomic_store(&lr[lrb + idx], rr,
                               __ATOMIC_RELAXED, __HIP_MEMORY_SCOPE_AGENT);
        }
    }
    __syncthreads();
    if (tid == 0) { __threadfence(); atomicAdd(cnt + p, 1); }
    if (sl != 0) return;
    if (tid == 0) barrier_wait(cnt + p, 10);
    __syncthreads();
    doKB(p, lr, tw, tmp4, tvp4, tep4, s_sw, s_sm, s_sv, s_sve,
         w2o, muo4, veo4, finalLvl, outw, outmu4, outvar4, tid);
}

// ---------------------------------------------------------------------------
// Launcher: 8 launches total.  ws layout (floats):
//   lr[64000] Aw2[128000] Amu[512000] Ave[512000]
//   Bw2[64000] Bmu[256000] Bve[256000] tveL[2000] tveR[2000] tveP[2000]
//   cnt[512 ints]
// ---------------------------------------------------------------------------
extern "C" void kernel_launch(void* const* d_in, const int* in_sizes, int n_in,
                              void* d_out, int out_size, void* d_ws, size_t ws_size,
                              hipStream_t stream) {
    (void)in_sizes; (void)n_in; (void)out_size; (void)ws_size;
    const float* sw      = (const float*)d_in[0];
    const float* smu     = (const float*)d_in[1];
    const float* svar    = (const float*)d_in[2];
    const float* tw      = (const float*)d_in[3];
    const float* tmu_p   = (const float*)d_in[4];
    const float* tmu_lc  = (const float*)d_in[5];
    const float* tmu_rc  = (const float*)d_in[6];
    const float* tvar_p  = (const float*)d_in[7];
    const float* tvar_lc = (const float*)d_in[8];
    const float* tvar_rc = (const float*)d_in[9];

    float* ws   = (float*)d_ws;
    float* lr   = ws;
    float* Aw2  = lr + 64000;
    float* Amu  = Aw2 + 128000;
    float* Ave  = Amu + 512000;
    float* Bw2  = Ave + 512000;
    float* Bmu  = Bw2 + 64000;
    float* Bve  = Bmu + 256000;
    float* tveL = Bve + 256000;
    float* tveR = tveL + 2000;
    float* tveP = tveR + 2000;
    int*   cnt  = (int*)(tveP + 2000);
    float* out  = (float*)d_out;

    hipLaunchKernelGGL(kP, dim3(8), dim3(256), 0, stream,
                       tvar_lc, tvar_rc, tvar_p, tveL, tveR, tveP, cnt);

    hipLaunchKernelGGL(kL1, dim3(128), dim3(256), 0, stream,
                       sw, smu, svar,
                       (const float4*)tmu_lc, (const float4*)tveL,
                       (const float4*)tmu_rc, (const float4*)tveR,
                       lr, cnt,
                       tw, (const float4*)tmu_p, (const float4*)tvar_p,
                       (const float4*)tveP, 128,
                       Aw2, (float4*)Amu, (float4*)Ave);

    float *cw2 = Aw2, *cmu = Amu, *cve = Ave;
    float *ow2 = Bw2, *omu = Bmu, *ove = Bve;
    int off = 192;
    int lvl = 1;
    for (int lg = 5; lg >= 0; --lg) {
        int m = 1 << lg;
        int fin = (m == 1);
        hipLaunchKernelGGL(kLvl, dim3(10 * m), dim3(256), 0, stream,
                           cw2, (const float4*)cmu, (const float4*)cve,
                           tmu_lc, tveL, tmu_rc, tveR,
                           lr, cnt + lvl * 64, lg,
                           tw, (const float4*)tmu_p, (const float4*)tvar_p,
                           (const float4*)tveP,
                           sw, smu, svar, off,
                           ow2, (float4*)omu, (float4*)ove,
                           fin, out, (float4*)(out + 2000), (float4*)(out + 10000));
        off += m;
        ++lvl;
        float* t;
        t = cw2; cw2 = ow2; ow2 = t;
        t = cmu; cmu = omu; omu = t;
        t = cve; cve = ove; ove = t;
    }
}

// Round 4
// 146.443 us; speedup vs baseline: 1.4398x; 1.4398x over previous
//
#include <hip/hip_runtime.h>
#include <math.h>

#define HALF_L2PI4 3.6757541328186906f   // 2*log(2*pi)
#define LOG2E      1.4426950408889634f
#define LN2        0.6931471805599453f
#define C_HQ       0.7213475204444817f   // 0.5*log2(e)

__device__ __forceinline__ float frcp(float x)  { return __builtin_amdgcn_rcpf(x); }
__device__ __forceinline__ float flog2(float x) { return __builtin_amdgcn_logf(x); }
__device__ __forceinline__ float fexp2(float x) { return __builtin_amdgcn_exp2f(x); }

// ---------------------------------------------------------------------------
// kP: zero barrier counters; precompute exp(2*trans_var_*) tables.
// ---------------------------------------------------------------------------
__global__ __launch_bounds__(256) void kP(
    const float* __restrict__ a, const float* __restrict__ b,
    const float* __restrict__ c,
    float* __restrict__ oa, float* __restrict__ ob, float* __restrict__ oc,
    int* __restrict__ cnt)
{
    int i = blockIdx.x * 256 + threadIdx.x;
    if (i < 2000) {
        oa[i] = __expf(2.0f * a[i]);
        ob[i] = __expf(2.0f * b[i]);
        oc[i] = __expf(2.0f * c[i]);
    }
    if (i < 512) cnt[i] = 0;
}

// ---------------------------------------------------------------------------
// kB phase: combine lr(L)+lr(R)+tw, score vs parent state (gm_full).
// ---------------------------------------------------------------------------
__device__ __forceinline__ void gm_full_dim(
    float m1, float v1, float v1s, float m2, float v2, float v2s,
    float& scale, float& pmu, float& pvar, float& pve)
{
    float s  = v1s + v2s;
    float rs = frcp(s);
    float ls = flog2(s) * LN2;
    float df = m1 - m2;
    scale += ls + df * df * rs;
    pmu  = fmaf(m1, v2s, m2 * v1s) * rs;
    pvar = v1 + v2 - 0.5f * ls;
    pve  = v1s * v2s * rs;
}

__device__ __forceinline__ void doKB(
    int p, const float* __restrict__ lr, const float* __restrict__ tw,
    const float4* __restrict__ tm4, const float4* __restrict__ tv4,
    const float4* __restrict__ te4,
    const float* s_sw, const float* s_sm, const float* s_sv, const float* s_sve,
    float* __restrict__ w2o, float4* __restrict__ muo4, float4* __restrict__ veo4,
    int finalLvl, float* __restrict__ outw, float4* __restrict__ outmu4,
    float4* __restrict__ outvar4, int tid)
{
    const float* lrL = lr + (size_t)p * 1000;
    const float* lrR = lrL + 500;
    for (int e = tid; e < 2000; e += 256) {
        int c = e & 3, ks = (e >> 2) & 3, r = e >> 4;
        int lrc = r % 5, r2 = r / 5, llc = r2 % 5, lp = r2 / 5;
        int t4 = ((lp * 5 + llc) * 5 + lrc) * 4 + c;
        float csv = lrL[t4] + lrR[t4] + tw[t4];
        float4 m2 = tm4[t4], v2 = tv4[t4], e2 = te4[t4];
        int sidx = (lp * 4 + ks) * 4;
        float base = csv + s_sw[lp * 4 + ks] - HALF_L2PI4;
        float scale = 0.f;
        float4 pmu, pvar, pve;
        gm_full_dim(s_sm[sidx+0], s_sv[sidx+0], s_sve[sidx+0], m2.x, v2.x, e2.x, scale, pmu.x, pvar.x, pve.x);
        gm_full_dim(s_sm[sidx+1], s_sv[sidx+1], s_sve[sidx+1], m2.y, v2.y, e2.y, scale, pmu.y, pvar.y, pve.y);
        gm_full_dim(s_sm[sidx+2], s_sv[sidx+2], s_sve[sidx+2], m2.z, v2.z, e2.z, scale, pmu.z, pvar.z, pve.z);
        gm_full_dim(s_sm[sidx+3], s_sv[sidx+3], s_sve[sidx+3], m2.w, v2.w, e2.w, scale, pmu.w, pvar.w, pve.w);
        float w = fmaf(-0.5f, scale, base);
        if (finalLvl) {
            outw[e]    = w;
            outmu4[e]  = pmu;
            outvar4[e] = pvar;
        } else {
            size_t ob = (size_t)p * 2000 + e;
            w2o[ob]  = (w - HALF_L2PI4) * LOG2E;
            muo4[ob] = pmu;
            veo4[ob] = pve;
        }
    }
}

// ---------------------------------------------------------------------------
// kL1: level-1 (children = leaves, K=4). block = child node (bid = 2p+side).
// Last arriver of the 2 siblings runs the kB phase.
// ---------------------------------------------------------------------------
__global__ __launch_bounds__(256) void kL1(
    const float* __restrict__ sw, const float* __restrict__ smu,
    const float* __restrict__ svar,
    const float4* __restrict__ tmL4, const float4* __restrict__ tvL4,
    const float4* __restrict__ tmR4, const float4* __restrict__ tvR4,
    float* __restrict__ lr, int* __restrict__ cnt,
    const float* __restrict__ tw, const float4* __restrict__ tmp4,
    const float4* __restrict__ tvp4, const float4* __restrict__ tep4,
    int off,
    float* __restrict__ w2o, float4* __restrict__ muo4, float4* __restrict__ veo4)
{
    int bid = blockIdx.x, p = bid >> 1, side = bid & 1, cn = bid;
    int tid = threadIdx.x;
    __shared__ float s_cm[80], s_cve[80], s_cw2[20];
    __shared__ float s_sw[20], s_sm[80], s_sv[80], s_sve[80];
    __shared__ int s_last;
    if (tid < 80) {
        s_cm[tid]  = smu[cn * 80 + tid];
        s_cve[tid] = __expf(2.f * svar[cn * 80 + tid]);
        if (tid < 20) s_cw2[tid] = (sw[cn * 20 + tid] - HALF_L2PI4) * LOG2E;
    }
    __syncthreads();
    const float4* tm = side ? tmR4 : tmL4;
    const float4* tv = side ? tvR4 : tvL4;
    for (int e = tid; e < 500; e += 256) {
        int c = e & 3, r = e >> 2;
        int lo = r % 5, r2 = r / 5, lp = r2 % 5, lc2 = r2 / 5;
        int idx = side ? (((lp * 5 + lo) * 5 + lc2) * 4 + c)
                       : (((lp * 5 + lc2) * 5 + lo) * 4 + c);
        float4 tmo = tm[idx], tvo = tv[idx];
        float vals[4];
        #pragma unroll
        for (int k = 0; k < 4; ++k) {
            int ci = (lc2 * 4 + k) * 4;
            float s0 = s_cve[ci+0] + tvo.x, s1 = s_cve[ci+1] + tvo.y;
            float s2 = s_cve[ci+2] + tvo.z, s3 = s_cve[ci+3] + tvo.w;
            float d0 = s_cm[ci+0] - tmo.x, d1 = s_cm[ci+1] - tmo.y;
            float d2 = s_cm[ci+2] - tmo.z, d3 = s_cm[ci+3] - tmo.w;
            float p01 = s0 * s1, p23 = s2 * s3;
            float q01 = fmaf(d0 * d0, s1, d1 * d1 * s0);
            float q23 = fmaf(d2 * d2, s3, d3 * d3 * s2);
            float P = p01 * p23;
            float Q = fmaf(q01, p23, q23 * p01);
            vals[k] = fmaf(-0.5f, flog2(P), fmaf(-C_HQ, Q * frcp(P), s_cw2[lc2 * 4 + k]));
        }
        float M = fmaxf(fmaxf(vals[0], vals[1]), fmaxf(vals[2], vals[3]));
        float S = fexp2(vals[0]-M) + fexp2(vals[1]-M)
                + fexp2(vals[2]-M) + fexp2(vals[3]-M);
        lr[(size_t)cn * 500 + idx] = (M + flog2(S)) * LN2;
    }
    __syncthreads();
    if (tid == 0) {
        int old = __hip_atomic_fetch_add(cnt + p, 1, __ATOMIC_RELEASE,
                                         __HIP_MEMORY_SCOPE_AGENT);
        s_last = (old == 1);
    }
    __syncthreads();
    if (!s_last) return;
    __builtin_amdgcn_fence(__ATOMIC_ACQUIRE, "agent");
    int node = off + p;
    if (tid < 80) {
        s_sm[tid] = smu[node * 80 + tid];
        float v = svar[node * 80 + tid];
        s_sv[tid] = v; s_sve[tid] = __expf(2.f * v);
        if (tid < 20) s_sw[tid] = sw[node * 20 + tid];
    }
    __syncthreads();
    doKB(p, lr, tw, tmp4, tvp4, tep4, s_sw, s_sm, s_sv, s_sve,
         w2o, muo4, veo4, 0, nullptr, nullptr, nullptr, tid);
}

// ---------------------------------------------------------------------------
// kLvl: K=400 level. block = (p, side, lc, lp), grid 50*m. Each wave owns 5
// outputs; pass 1 streams 7 fragment slots computing vals[5][7] + running max;
// pass 2 reduces (chains interleaved across the 5 outputs for ILP).
// Last arriver of the 50 sibling blocks runs the kB phase.
// ---------------------------------------------------------------------------
__global__ __launch_bounds__(256) void kLvl(
    const float* __restrict__ cw2, const float4* __restrict__ cmu4,
    const float4* __restrict__ cve4,
    const float4* __restrict__ tmL4, const float4* __restrict__ tvL4,
    const float4* __restrict__ tmR4, const float4* __restrict__ tvR4,
    float* __restrict__ lr, int* __restrict__ cnt, int log2m,
    const float* __restrict__ tw, const float4* __restrict__ tmp4,
    const float4* __restrict__ tvp4, const float4* __restrict__ tep4,
    const float* __restrict__ sw_all, const float* __restrict__ smu,
    const float* __restrict__ svar, int off,
    float* __restrict__ w2o, float4* __restrict__ muo4, float4* __restrict__ veo4,
    int finalLvl, float* __restrict__ outw, float4* __restrict__ outmu4,
    float4* __restrict__ outvar4)
{
    int bid = blockIdx.x;
    int p = bid & ((1 << log2m) - 1), sl = bid >> log2m;
    int side = (sl >= 25) ? 1 : 0;
    int r0 = sl - side * 25;
    int lc = r0 / 5, lp = r0 - lc * 5;
    int tid = threadIdx.x, lane = tid & 63, wave = tid >> 6;
    int cn = 2 * p + side;

    __shared__ float s_sw[20], s_sm[80], s_sv[80], s_sve[80];
    __shared__ int s_last;

    const float4* cmb = cmu4 + (size_t)(cn * 5 + lc) * 400;
    const float4* cvb = cve4 + (size_t)(cn * 5 + lc) * 400;
    const float*  cwb = cw2  + (size_t)(cn * 5 + lc) * 400;
    const float4* tmf = side ? tmR4 : tmL4;
    const float4* tvf = side ? tvR4 : tvL4;

    int idxs[5];
    float4 tmo[5], tvo[5];
    #pragma unroll
    for (int j = 0; j < 5; ++j) {
        int o = wave + 4 * j, lo = o >> 2, c = o & 3;
        int idx = side ? (((lp * 5 + lo) * 5 + lc) * 4 + c)
                       : (((lp * 5 + lc) * 5 + lo) * 4 + c);
        idxs[j] = idx;
        tmo[j] = tmf[idx];
        tvo[j] = tvf[idx];
    }

    float vals[5][7], M[5];
    #pragma unroll
    for (int i = 0; i < 7; ++i) {
        int kk = lane + (i << 6);
        int k = kk < 400 ? kk : 399;
        float4 cm = cmb[k], cv = cvb[k];
        float wv = kk < 400 ? cwb[kk] : -1e30f;
        #pragma unroll
        for (int j = 0; j < 5; ++j) {
            float s0 = cv.x + tvo[j].x, s1 = cv.y + tvo[j].y;
            float s2 = cv.z + tvo[j].z, s3 = cv.w + tvo[j].w;
            float d0 = cm.x - tmo[j].x, d1 = cm.y - tmo[j].y;
            float d2 = cm.z - tmo[j].z, d3 = cm.w - tmo[j].w;
            float p01 = s0 * s1, p23 = s2 * s3;
            float q01 = fmaf(d0 * d0, s1, d1 * d1 * s0);
            float q23 = fmaf(d2 * d2, s3, d3 * d3 * s2);
            float P = p01 * p23;
            float Q = fmaf(q01, p23, q23 * p01);
            float v = fmaf(-0.5f, flog2(P), fmaf(-C_HQ, Q * frcp(P), wv));
            vals[j][i] = v;
            M[j] = (i == 0) ? v : fmaxf(M[j], v);
        }
    }
    // cross-lane max, 5 chains interleaved
    #pragma unroll
    for (int s = 32; s; s >>= 1) {
        #pragma unroll
        for (int j = 0; j < 5; ++j) M[j] = fmaxf(M[j], __shfl_xor(M[j], s));
    }
    float S[5];
    #pragma unroll
    for (int j = 0; j < 5; ++j) {
        float a0 = fexp2(vals[j][0] - M[j]) + fexp2(vals[j][1] - M[j]);
        float a1 = fexp2(vals[j][2] - M[j]) + fexp2(vals[j][3] - M[j]);
        float a2 = fexp2(vals[j][4] - M[j]) + fexp2(vals[j][5] - M[j]);
        S[j] = a0 + a1 + a2 + fexp2(vals[j][6] - M[j]);
    }
    #pragma unroll
    for (int s = 32; s; s >>= 1) {
        #pragma unroll
        for (int j = 0; j < 5; ++j) S[j] += __shfl_xor(S[j], s);
    }
    if (lane == 0) {
        size_t lrb = (size_t)cn * 500;
        #pragma unroll
        for (int j = 0; j < 5; ++j)
            lr[lrb + idxs[j]] = (M[j] + flog2(S[j])) * LN2;
    }

    __syncthreads();
    if (tid == 0) {
        int old = __hip_atomic_fetch_add(cnt + p, 1, __ATOMIC_RELEASE,
                                         __HIP_MEMORY_SCOPE_AGENT);
        s_last = (old == 49);
    }
    __syncthreads();
    if (!s_last) return;
    __builtin_amdgcn_fence(__ATOMIC_ACQUIRE, "agent");
    int node = off + p;
    if (tid < 80) {
        s_sm[tid] = smu[node * 80 + tid];
        float v = svar[node * 80 + tid];
        s_sv[tid] = v; s_sve[tid] = __expf(2.f * v);
        if (tid < 20) s_sw[tid] = sw_all[node * 20 + tid];
    }
    __syncthreads();
    doKB(p, lr, tw, tmp4, tvp4, tep4, s_sw, s_sm, s_sv, s_sve,
         w2o, muo4, veo4, finalLvl, outw, outmu4, outvar4, tid);
}

// ---------------------------------------------------------------------------
// Launcher: 8 launches. ws layout (floats):
//   lr[64000] Aw2[128000] Amu[512000] Ave[512000]
//   Bw2[64000] Bmu[256000] Bve[256000] tveL[2000] tveR[2000] tveP[2000]
//   cnt[512 ints]
// ---------------------------------------------------------------------------
extern "C" void kernel_launch(void* const* d_in, const int* in_sizes, int n_in,
                              void* d_out, int out_size, void* d_ws, size_t ws_size,
                              hipStream_t stream) {
    (void)in_sizes; (void)n_in; (void)out_size; (void)ws_size;
    const float* sw      = (const float*)d_in[0];
    const float* smu     = (const float*)d_in[1];
    const float* svar    = (const float*)d_in[2];
    const float* tw      = (const float*)d_in[3];
    const float* tmu_p   = (const float*)d_in[4];
    const float* tmu_lc  = (const float*)d_in[5];
    const float* tmu_rc  = (const float*)d_in[6];
    const float* tvar_p  = (const float*)d_in[7];
    const float* tvar_lc = (const float*)d_in[8];
    const float* tvar_rc = (const float*)d_in[9];

    float* ws   = (float*)d_ws;
    float* lr   = ws;
    float* Aw2  = lr + 64000;
    float* Amu  = Aw2 + 128000;
    float* Ave  = Amu + 512000;
    float* Bw2  = Ave + 512000;
    float* Bmu  = Bw2 + 64000;
    float* Bve  = Bmu + 256000;
    float* tveL = Bve + 256000;
    float* tveR = tveL + 2000;
    float* tveP = tveR + 2000;
    int*   cnt  = (int*)(tveP + 2000);
    float* out  = (float*)d_out;

    hipLaunchKernelGGL(kP, dim3(8), dim3(256), 0, stream,
                       tvar_lc, tvar_rc, tvar_p, tveL, tveR, tveP, cnt);

    hipLaunchKernelGGL(kL1, dim3(128), dim3(256), 0, stream,
                       sw, smu, svar,
                       (const float4*)tmu_lc, (const float4*)tveL,
                       (const float4*)tmu_rc, (const float4*)tveR,
                       lr, cnt,
                       tw, (const float4*)tmu_p, (const float4*)tvar_p,
                       (const float4*)tveP, 128,
                       Aw2, (float4*)Amu, (float4*)Ave);

    float *cw2 = Aw2, *cmu = Amu, *cve = Ave;
    float *ow2 = Bw2, *omu = Bmu, *ove = Bve;
    int off = 192;
    int lvl = 1;
    for (int lg = 5; lg >= 0; --lg) {
        int m = 1 << lg;
        int fin = (m == 1);
        hipLaunchKernelGGL(kLvl, dim3(50 * m), dim3(256), 0, stream,
                           cw2, (const float4*)cmu, (const float4*)cve,
                           (const float4*)tmu_lc, (const float4*)tveL,
                           (const float4*)tmu_rc, (const float4*)tveR,
                           lr, cnt + lvl * 64, lg,
                           tw, (const float4*)tmu_p, (const float4*)tvar_p,
                           (const float4*)tveP,
                           sw, smu, svar, off,
                           ow2, (float4*)omu, (float4*)ove,
                           fin, out, (float4*)(out + 2000), (float4*)(out + 10000));
        off += m;
        ++lvl;
        float* t;
        t = cw2; cw2 = ow2; ow2 = t;
        t = cmu; cmu = omu; omu = t;
        t = cve; cve = ove; ove = t;
    }
}

// Round 5
// 80.684 us; speedup vs baseline: 2.6133x; 1.8150x over previous
//
#include <hip/hip_runtime.h>
#include <math.h>

#define L2PI4      7.3515082656373812f   // 4*log(2*pi)
#define HALF_L2PI4 3.6757541328186906f   // 2*log(2*pi)
#define LOG2E      1.4426950408889634f
#define LN2        0.6931471805599453f
#define C_HQ       0.7213475204444817f   // 0.5*log2(e)

__device__ __forceinline__ float frcp(float x)  { return __builtin_amdgcn_rcpf(x); }
__device__ __forceinline__ float flog2(float x) { return __builtin_amdgcn_logf(x); }
__device__ __forceinline__ float fexp2(float x) { return __builtin_amdgcn_exp2f(x); }

// ---------------------------------------------------------------------------
// kL1: lr for the 128 leaf children (K=4, mixture = state directly).
// Side-band: blocks 0..7 precompute tveP = exp(2*trans_var_p) (8000 floats).
// lr[cn*500 + t4], t4 = ((lp*5+llc)*5+lrc)*4+c, natural-log domain.
// ---------------------------------------------------------------------------
__global__ __launch_bounds__(256) void kL1(
    const float* __restrict__ sw, const float* __restrict__ smu,
    const float* __restrict__ svar,
    const float4* __restrict__ tmL4, const float4* __restrict__ tvL4,
    const float4* __restrict__ tmR4, const float4* __restrict__ tvR4,
    const float* __restrict__ tvarp, float* __restrict__ tveP,
    float* __restrict__ lr)
{
    int cn = blockIdx.x, side = cn & 1, tid = threadIdx.x;
    if (cn < 8) {
        for (int i = tid; i < 1000; i += 256) {
            int j = cn * 1000 + i;
            tveP[j] = __expf(2.f * tvarp[j]);
        }
    }
    __shared__ float s_cm[80], s_cve[80], s_cw2[20];
    if (tid < 80) {
        s_cm[tid]  = smu[cn * 80 + tid];
        s_cve[tid] = __expf(2.f * svar[cn * 80 + tid]);
        if (tid < 20) s_cw2[tid] = (sw[cn * 20 + tid] - HALF_L2PI4) * LOG2E;
    }
    __syncthreads();
    const float4* tm = side ? tmR4 : tmL4;
    const float4* tv = side ? tvR4 : tvL4;
    for (int e = tid; e < 500; e += 256) {
        int c = e & 3, r = e >> 2;
        int lo = r % 5, r2 = r / 5, lp = r2 % 5, lc2 = r2 / 5;
        int idx = side ? (((lp * 5 + lo) * 5 + lc2) * 4 + c)
                       : (((lp * 5 + lc2) * 5 + lo) * 4 + c);
        float4 tmo = tm[idx];
        float4 tvr = tv[idx];
        float4 tvo = make_float4(__expf(2.f * tvr.x), __expf(2.f * tvr.y),
                                 __expf(2.f * tvr.z), __expf(2.f * tvr.w));
        float vals[4];
        #pragma unroll
        for (int k = 0; k < 4; ++k) {
            int ci = (lc2 * 4 + k) * 4;
            float s0 = s_cve[ci+0] + tvo.x, s1 = s_cve[ci+1] + tvo.y;
            float s2 = s_cve[ci+2] + tvo.z, s3 = s_cve[ci+3] + tvo.w;
            float d0 = s_cm[ci+0] - tmo.x, d1 = s_cm[ci+1] - tmo.y;
            float d2 = s_cm[ci+2] - tmo.z, d3 = s_cm[ci+3] - tmo.w;
            float p01 = s0 * s1, p23 = s2 * s3;
            float q01 = fmaf(d0 * d0, s1, d1 * d1 * s0);
            float q23 = fmaf(d2 * d2, s3, d3 * d3 * s2);
            float P = p01 * p23;
            float Q = fmaf(q01, p23, q23 * p01);
            vals[k] = fmaf(-0.5f, flog2(P), fmaf(-C_HQ, Q * frcp(P), s_cw2[lc2 * 4 + k]));
        }
        float M = fmaxf(fmaxf(vals[0], vals[1]), fmaxf(vals[2], vals[3]));
        float S = fexp2(vals[0]-M) + fexp2(vals[1]-M)
                + fexp2(vals[2]-M) + fexp2(vals[3]-M);
        lr[(size_t)cn * 500 + idx] = (M + flog2(S)) * LN2;
    }
}

// ---------------------------------------------------------------------------
// kAB: one launch per parent-level m. block = (p, side, lc, lp), grid 50*m.
// Phase 1: rebuild child cn's 400-comp mixture (w2, mu, ve) IN REGISTERS from
//          lr_prev(2cn), lr_prev(2cn+1) + trans_p + state(childOff+cn), label lc.
// Phase 2: lse over the 400 comps for 5 (lo,c) outputs per wave -> lr_cur(cn).
// No atomics/fences; cross-level sync = kernel boundary.
// ---------------------------------------------------------------------------
__global__ __launch_bounds__(256) void kAB(
    const float* __restrict__ lrP, float* __restrict__ lrC,
    const float* __restrict__ sw, const float* __restrict__ smu,
    const float* __restrict__ svar, int childOff,
    const float* __restrict__ tw, const float4* __restrict__ tmp4,
    const float4* __restrict__ tep4,
    const float4* __restrict__ tmL4, const float4* __restrict__ tvL4,
    const float4* __restrict__ tmR4, const float4* __restrict__ tvR4,
    int log2m)
{
    int bid = blockIdx.x;
    int p = bid & ((1 << log2m) - 1), sl = bid >> log2m;
    int side = (sl >= 25) ? 1 : 0;
    int r0 = sl - side * 25;
    int lc = r0 / 5, lp = r0 - lc * 5;
    int tid = threadIdx.x, lane = tid & 63, wave = tid >> 6;
    int cn = 2 * p + side;
    int node = childOff + cn;

    __shared__ float s_sm[16], s_sve[16], s_swl[4];
    if (tid < 16) {
        s_sm[tid]  = smu[node * 80 + lc * 16 + tid];
        s_sve[tid] = __expf(2.f * svar[node * 80 + lc * 16 + tid]);
        if (tid < 4) s_swl[tid] = sw[node * 20 + lc * 4 + tid];
    }
    __syncthreads();

    const float* lrL = lrP + (size_t)(2 * cn) * 500;
    const float* lrR = lrP + (size_t)(2 * cn + 1) * 500;

    // ---- Phase 1: child fragment in registers --------------------------
    float w2r[7]; float4 cm[7], cve[7];
    #pragma unroll
    for (int i = 0; i < 7; ++i) {
        int kk = lane + (i << 6);
        int k = kk < 400 ? kk : 399;
        int c2 = k & 3, ks = (k >> 2) & 3, r = k >> 4;     // r = llc2*5+lrc2
        int t4 = (lc * 25 + r) * 4 + c2;
        float csv = lrL[t4] + lrR[t4] + tw[t4];
        float4 m2 = tmp4[t4], e2 = tep4[t4];
        float base2 = (csv + s_swl[ks] - L2PI4) * LOG2E;   // incl. next-level pre-sub
        float L = 0.f, Qn = 0.f;
        float4 mu, ve;
        {
            float v1s = s_sve[ks*4+0], m1 = s_sm[ks*4+0];
            float s = v1s + e2.x, rs = frcp(s), df = m1 - m2.x;
            L += flog2(s); Qn = fmaf(df * df, rs, Qn);
            mu.x = fmaf(m1, e2.x, m2.x * v1s) * rs; ve.x = v1s * e2.x * rs;
        }
        {
            float v1s = s_sve[ks*4+1], m1 = s_sm[ks*4+1];
            float s = v1s + e2.y, rs = frcp(s), df = m1 - m2.y;
            L += flog2(s); Qn = fmaf(df * df, rs, Qn);
            mu.y = fmaf(m1, e2.y, m2.y * v1s) * rs; ve.y = v1s * e2.y * rs;
        }
        {
            float v1s = s_sve[ks*4+2], m1 = s_sm[ks*4+2];
            float s = v1s + e2.z, rs = frcp(s), df = m1 - m2.z;
            L += flog2(s); Qn = fmaf(df * df, rs, Qn);
            mu.z = fmaf(m1, e2.z, m2.z * v1s) * rs; ve.z = v1s * e2.z * rs;
        }
        {
            float v1s = s_sve[ks*4+3], m1 = s_sm[ks*4+3];
            float s = v1s + e2.w, rs = frcp(s), df = m1 - m2.w;
            L += flog2(s); Qn = fmaf(df * df, rs, Qn);
            mu.w = fmaf(m1, e2.w, m2.w * v1s) * rs; ve.w = v1s * e2.w * rs;
        }
        w2r[i] = (kk < 400) ? fmaf(-0.5f, fmaf(Qn, LOG2E, L), base2) : -1e30f;
        cm[i] = mu; cve[i] = ve;
    }

    // ---- Phase 2: lse over 400 comps, 5 outputs per wave ---------------
    const float4* tmf = side ? tmR4 : tmL4;
    const float4* tvf = side ? tvR4 : tvL4;
    int idxs[5];
    float4 tmo[5], tvo[5];
    #pragma unroll
    for (int j = 0; j < 5; ++j) {
        int o = wave + 4 * j, lo = o >> 2, c = o & 3;
        int idx = side ? (((lp * 5 + lo) * 5 + lc) * 4 + c)
                       : (((lp * 5 + lc) * 5 + lo) * 4 + c);
        idxs[j] = idx;
        tmo[j] = tmf[idx];
        float4 tvr = tvf[idx];
        tvo[j] = make_float4(__expf(2.f * tvr.x), __expf(2.f * tvr.y),
                             __expf(2.f * tvr.z), __expf(2.f * tvr.w));
    }

    float vals[5][7], M[5];
    #pragma unroll
    for (int i = 0; i < 7; ++i) {
        #pragma unroll
        for (int j = 0; j < 5; ++j) {
            float s0 = cve[i].x + tvo[j].x, s1 = cve[i].y + tvo[j].y;
            float s2 = cve[i].z + tvo[j].z, s3 = cve[i].w + tvo[j].w;
            float d0 = cm[i].x - tmo[j].x, d1 = cm[i].y - tmo[j].y;
            float d2 = cm[i].z - tmo[j].z, d3 = cm[i].w - tmo[j].w;
            float p01 = s0 * s1, p23 = s2 * s3;
            float q01 = fmaf(d0 * d0, s1, d1 * d1 * s0);
            float q23 = fmaf(d2 * d2, s3, d3 * d3 * s2);
            float P = p01 * p23;
            float Q = fmaf(q01, p23, q23 * p01);
            float v = fmaf(-0.5f, flog2(P), fmaf(-C_HQ, Q * frcp(P), w2r[i]));
            vals[j][i] = v;
            M[j] = (i == 0) ? v : fmaxf(M[j], v);
        }
    }
    #pragma unroll
    for (int s = 32; s; s >>= 1) {
        #pragma unroll
        for (int j = 0; j < 5; ++j) M[j] = fmaxf(M[j], __shfl_xor(M[j], s));
    }
    float S[5];
    #pragma unroll
    for (int j = 0; j < 5; ++j) {
        float a0 = fexp2(vals[j][0] - M[j]) + fexp2(vals[j][1] - M[j]);
        float a1 = fexp2(vals[j][2] - M[j]) + fexp2(vals[j][3] - M[j]);
        float a2 = fexp2(vals[j][4] - M[j]) + fexp2(vals[j][5] - M[j]);
        S[j] = a0 + a1 + a2 + fexp2(vals[j][6] - M[j]);
    }
    #pragma unroll
    for (int s = 32; s; s >>= 1) {
        #pragma unroll
        for (int j = 0; j < 5; ++j) S[j] += __shfl_xor(S[j], s);
    }
    if (lane == 0) {
        size_t lrb = (size_t)cn * 500;
        #pragma unroll
        for (int j = 0; j < 5; ++j)
            lrC[lrb + idxs[j]] = (M[j] + flog2(S[j])) * LN2;
    }
}

// ---------------------------------------------------------------------------
// kFin: root mixture (w, mu, var) -> d_out. 2000 outputs, one per thread.
// ---------------------------------------------------------------------------
__global__ __launch_bounds__(256) void kFin(
    const float* __restrict__ lrC,
    const float* __restrict__ sw, const float* __restrict__ smu,
    const float* __restrict__ svar, int rootNode,
    const float* __restrict__ tw, const float4* __restrict__ tmp4,
    const float4* __restrict__ tvp4, const float4* __restrict__ tep4,
    float* __restrict__ outw, float4* __restrict__ outmu4,
    float4* __restrict__ outvar4)
{
    int e = blockIdx.x * 256 + threadIdx.x;
    if (e >= 2000) return;
    int c = e & 3, ks = (e >> 2) & 3, r = e >> 4;
    int lrc = r % 5, r2 = r / 5, llc = r2 % 5, lp = r2 / 5;
    int t4 = ((lp * 5 + llc) * 5 + lrc) * 4 + c;
    float csv = lrC[t4] + lrC[500 + t4] + tw[t4];
    float4 m2 = tmp4[t4], v2 = tvp4[t4], e2 = tep4[t4];
    int sb = rootNode * 80 + (lp * 4 + ks) * 4;
    float base = csv + sw[rootNode * 20 + lp * 4 + ks] - HALF_L2PI4;
    float scale = 0.f;
    float4 pmu, pvar;
    {
        float m1 = smu[sb+0], v1 = svar[sb+0], v1s = __expf(2.f * v1);
        float s = v1s + e2.x, rs = frcp(s), ls = flog2(s) * LN2, df = m1 - m2.x;
        scale += ls + df * df * rs;
        pmu.x = fmaf(m1, e2.x, m2.x * v1s) * rs; pvar.x = v1 + v2.x - 0.5f * ls;
    }
    {
        float m1 = smu[sb+1], v1 = svar[sb+1], v1s = __expf(2.f * v1);
        float s = v1s + e2.y, rs = frcp(s), ls = flog2(s) * LN2, df = m1 - m2.y;
        scale += ls + df * df * rs;
        pmu.y = fmaf(m1, e2.y, m2.y * v1s) * rs; pvar.y = v1 + v2.y - 0.5f * ls;
    }
    {
        float m1 = smu[sb+2], v1 = svar[sb+2], v1s = __expf(2.f * v1);
        float s = v1s + e2.z, rs = frcp(s), ls = flog2(s) * LN2, df = m1 - m2.z;
        scale += ls + df * df * rs;
        pmu.z = fmaf(m1, e2.z, m2.z * v1s) * rs; pvar.z = v1 + v2.z - 0.5f * ls;
    }
    {
        float m1 = smu[sb+3], v1 = svar[sb+3], v1s = __expf(2.f * v1);
        float s = v1s + e2.w, rs = frcp(s), ls = flog2(s) * LN2, df = m1 - m2.w;
        scale += ls + df * df * rs;
        pmu.w = fmaf(m1, e2.w, m2.w * v1s) * rs; pvar.w = v1 + v2.w - 0.5f * ls;
    }
    outw[e]    = fmaf(-0.5f, scale, base);
    outmu4[e]  = pmu;
    outvar4[e] = pvar;
}

// ---------------------------------------------------------------------------
// Launcher: 8 launches, no atomics. ws layout (floats):
//   lrA[64000] lrB[64000] tveP[8000]
// ---------------------------------------------------------------------------
extern "C" void kernel_launch(void* const* d_in, const int* in_sizes, int n_in,
                              void* d_out, int out_size, void* d_ws, size_t ws_size,
                              hipStream_t stream) {
    (void)in_sizes; (void)n_in; (void)out_size; (void)ws_size;
    const float* sw      = (const float*)d_in[0];
    const float* smu     = (const float*)d_in[1];
    const float* svar    = (const float*)d_in[2];
    const float* tw      = (const float*)d_in[3];
    const float* tmu_p   = (const float*)d_in[4];
    const float* tmu_lc  = (const float*)d_in[5];
    const float* tmu_rc  = (const float*)d_in[6];
    const float* tvar_p  = (const float*)d_in[7];
    const float* tvar_lc = (const float*)d_in[8];
    const float* tvar_rc = (const float*)d_in[9];

    float* ws   = (float*)d_ws;
    float* lrA  = ws;
    float* lrB  = lrA + 64000;
    float* tveP = lrB + 64000;
    float* out  = (float*)d_out;

    hipLaunchKernelGGL(kL1, dim3(128), dim3(256), 0, stream,
                       sw, smu, svar,
                       (const float4*)tmu_lc, (const float4*)tvar_lc,
                       (const float4*)tmu_rc, (const float4*)tvar_rc,
                       tvar_p, tveP, lrA);

    // (m, childOff): children of level-m parents live at childOff..childOff+2m-1
    const int childOffs[6] = {128, 192, 224, 240, 248, 252};
    float* lrP = lrA;
    float* lrC = lrB;
    int li = 0;
    for (int lg = 5; lg >= 0; --lg, ++li) {
        int m = 1 << lg;
        hipLaunchKernelGGL(kAB, dim3(50 * m), dim3(256), 0, stream,
                           lrP, lrC,
                           sw, smu, svar, childOffs[li],
                           tw, (const float4*)tmu_p, (const float4*)tveP,
                           (const float4*)tmu_lc, (const float4*)tvar_lc,
                           (const float4*)tmu_rc, (const float4*)tvar_rc,
                           lg);
        float* t = lrP; lrP = lrC; lrC = t;
    }
    // after loop, last level's output is in lrP (entries 0,1)
    hipLaunchKernelGGL(kFin, dim3(8), dim3(256), 0, stream,
                       lrP, sw, smu, svar, 254,
                       tw, (const float4*)tmu_p, (const float4*)tvar_p,
                       (const float4*)tveP,
                       out, (float4*)(out + 2000), (float4*)(out + 10000));
}